// Round 1
// baseline (1498.798 us; speedup 1.0000x reference)
//
#include <hip/hip_runtime.h>
#include <hip/hip_fp16.h>

typedef _Float16 f16;
typedef f16 f16x8 __attribute__((ext_vector_type(8)));
typedef float f32x4 __attribute__((ext_vector_type(4)));

#define NPIX 16384
#define DDIM 256
#define KCB  8192
#define KCAT 768

// ---- async global->LDS (16B per lane, lane-contiguous LDS dest) ----
__device__ __forceinline__ void lds_async16(const void* g, void* l) {
    __builtin_amdgcn_global_load_lds(
        (const __attribute__((address_space(1))) unsigned int*)g,
        (__attribute__((address_space(3))) unsigned int*)l,
        16, 0, 0);
}

// ---- init scratch (ws re-poisoned 0xAA before every call) ----
__global__ void init_k(float* gsum, unsigned long long* gmin) {
    int i = blockIdx.x * 256 + threadIdx.x;
    if (i < NPIX) { gsum[i] = 0.f; gmin[i] = ~0ULL; }
}

// ---- split x into fp16 hi/lo, packed [xh | xl | xh] per row (K=768) ----
__global__ void prep_x(const float* __restrict__ x, f16* __restrict__ Acat) {
    int p = blockIdx.x, d = threadIdx.x;
    float v = x[p * DDIM + d];
    f16 h = (f16)v;
    f16 lo = (f16)(v - (float)h);
    Acat[p * KCAT + d]        = h;
    Acat[p * KCAT + 256 + d]  = lo;
    Acat[p * KCAT + 512 + d]  = h;
}

// ---- split codebook, packed [ch | ch | cl]; also c2 = ||c||^2 ----
__global__ void prep_c(const float* __restrict__ cb, f16* __restrict__ Bcat,
                       float* __restrict__ c2) {
    int k = blockIdx.x, d = threadIdx.x;
    float v = cb[k * DDIM + d];
    f16 h = (f16)v;
    f16 lo = (f16)(v - (float)h);
    Bcat[k * KCAT + d]       = h;
    Bcat[k * KCAT + 256 + d] = h;
    Bcat[k * KCAT + 512 + d] = lo;
    float v2 = v * v;
    #pragma unroll
    for (int m = 32; m; m >>= 1) v2 += __shfl_xor(v2, m);
    __shared__ float ws4[4];
    if ((threadIdx.x & 63) == 0) ws4[threadIdx.x >> 6] = v2;
    __syncthreads();
    if (threadIdx.x == 0) c2[k] = ws4[0] + ws4[1] + ws4[2] + ws4[3];
}

// ---- transpose ch into chT[256][8192] f16 for gemm2 B-operand ----
__global__ void transpose_c(const f16* __restrict__ Bcat, f16* __restrict__ chT) {
    __shared__ f16 tile[64][68];
    int k0 = blockIdx.x * 64, d0 = blockIdx.y * 64;
    #pragma unroll
    for (int i = 0; i < 16; ++i) {
        int idx = i * 256 + threadIdx.x;
        int kl = idx >> 6, dl = idx & 63;
        tile[kl][dl] = Bcat[(k0 + kl) * KCAT + d0 + dl];
    }
    __syncthreads();
    #pragma unroll
    for (int i = 0; i < 16; ++i) {
        int idx = i * 256 + threadIdx.x;
        int dl = idx >> 6, kl = idx & 63;
        chT[(size_t)(d0 + dl) * KCB + k0 + kl] = tile[kl][dl];
    }
}

// ---- GEMM1: u = exp(2*x.c - c2 + noise) + row-sum + argmin ----
// 128x128 tile, BK=32, 4 waves (each 64x64), mfma_f32_16x16x32_f16
__global__ __launch_bounds__(256) void gemm1(
    const f16* __restrict__ A, const f16* __restrict__ B,
    const float* __restrict__ c2, const float* __restrict__ noise,
    float* __restrict__ U, float* __restrict__ gsum,
    unsigned long long* __restrict__ gmin)
{
    __shared__ f16 As[128 * 32];
    __shared__ f16 Bs[128 * 32];
    __shared__ float lsum[128];
    __shared__ unsigned long long lmin[128];

    const int tid = threadIdx.x;
    const int lane = tid & 63, wid = tid >> 6;
    const int bm = blockIdx.y, bn = blockIdx.x;
    const int wm = (wid & 1) * 64, wn = (wid >> 1) * 64;
    const int fr = lane & 15, fk = (lane >> 4) * 8;

    if (tid < 128) { lsum[tid] = 0.f; lmin[tid] = ~0ULL; }

    const f32x4 z = {0.f, 0.f, 0.f, 0.f};
    f32x4 acc[4][4];
    #pragma unroll
    for (int i = 0; i < 4; ++i)
        #pragma unroll
        for (int j = 0; j < 4; ++j) acc[i][j] = z;

    // staging map: thread t loads 16B; byte q=t*16 -> row=q/64, kbytes=q%64
    const int q = tid * 16;
    const int ar = q >> 6;                // 0..63
    const int ak = (q & 63) >> 1;         // half offset {0,8,16,24}
    const f16* Ab = A + (size_t)(bm * 128) * KCAT;
    const f16* Bb = B + (size_t)(bn * 128) * KCAT;

    for (int k0 = 0; k0 < KCAT; k0 += 32) {
        lds_async16(Ab + ar * KCAT + k0 + ak,        (char*)As + q);
        lds_async16(Ab + (ar + 64) * KCAT + k0 + ak, (char*)As + q + 4096);
        lds_async16(Bb + ar * KCAT + k0 + ak,        (char*)Bs + q);
        lds_async16(Bb + (ar + 64) * KCAT + k0 + ak, (char*)Bs + q + 4096);
        __syncthreads();
        f16x8 a[4], b[4];
        #pragma unroll
        for (int i = 0; i < 4; ++i) a[i] = *(const f16x8*)(As + (wm + i * 16 + fr) * 32 + fk);
        #pragma unroll
        for (int j = 0; j < 4; ++j) b[j] = *(const f16x8*)(Bs + (wn + j * 16 + fr) * 32 + fk);
        #pragma unroll
        for (int i = 0; i < 4; ++i)
            #pragma unroll
            for (int j = 0; j < 4; ++j)
                acc[i][j] = __builtin_amdgcn_mfma_f32_16x16x32_f16(a[i], b[j], acc[i][j], 0, 0, 0);
        __syncthreads();
    }

    // epilogue: C/D map col=lane&15, row=(lane>>4)*4+reg
    const int cbase = bn * 128 + wn + fr;
    float cc[4];
    #pragma unroll
    for (int j = 0; j < 4; ++j) cc[j] = c2[cbase + j * 16];
    const int rq = (lane >> 4) * 4;

    #pragma unroll
    for (int i = 0; i < 4; ++i) {
        #pragma unroll
        for (int r = 0; r < 4; ++r) {
            const int rowl = wm + i * 16 + rq + r;
            const int rowg = bm * 128 + rowl;
            const float* np_ = noise + (size_t)rowg * KCB + cbase;
            float* up = U + (size_t)rowg * KCB + cbase;
            float sum4 = 0.f;
            unsigned long long pk = ~0ULL;
            #pragma unroll
            for (int j = 0; j < 4; ++j) {
                const float xc = acc[i][j][r];
                const float t = 2.f * xc - cc[j] + np_[j * 16];
                const float u = __expf(t);
                up[j * 16] = u;
                sum4 += u;
                const float s = cc[j] - 2.f * xc;   // = dist - ||x||^2
                unsigned int bb = __float_as_uint(s);
                bb = (bb & 0x80000000u) ? ~bb : (bb | 0x80000000u);
                unsigned long long p =
                    ((unsigned long long)bb << 32) | (unsigned int)(cbase + j * 16);
                pk = p < pk ? p : pk;
            }
            #pragma unroll
            for (int m = 1; m <= 8; m <<= 1) {
                sum4 += __shfl_xor(sum4, m);
                unsigned long long op = __shfl_xor(pk, m);
                pk = op < pk ? op : pk;
            }
            if (fr == 0) {
                atomicAdd(&lsum[rowl], sum4);
                atomicMin(&lmin[rowl], pk);
            }
        }
    }
    __syncthreads();
    if (tid < 128) {
        atomicAdd(&gsum[bm * 128 + tid], lsum[tid]);
        atomicMin(&gmin[bm * 128 + tid], lmin[tid]);
    }
}

// ---- GEMM2: normalize u -> E (in place), quantized = E @ ch, write indices ----
// BM=32 rows, BN=256 (full D), BK=64; 4 waves each own 64 cols of D
__global__ __launch_bounds__(256) void gemm2(
    float* __restrict__ U, const f16* __restrict__ chT,
    const float* __restrict__ gsum, const unsigned long long* __restrict__ gmin,
    float* __restrict__ Q, float* __restrict__ IDX)
{
    __shared__ f16 As[32 * 72];            // padded stride 72 halves
    __shared__ f16 Bs[2 * 256 * 32];       // two K-halves, rows of 32 halves
    __shared__ float invl[32];

    const int tid = threadIdx.x, lane = tid & 63, wid = tid >> 6;
    const int r0 = blockIdx.x * 32;
    if (tid < 32) {
        invl[tid] = 1.0f / gsum[r0 + tid];
        IDX[r0 + tid] = (float)(unsigned int)(gmin[r0 + tid] & 0xFFFFFFFFull);
    }
    __syncthreads();

    const int arow = tid >> 3;
    const int akc = (tid & 7) * 8;
    const int fr = lane & 15, fk = (lane >> 4) * 8;

    const f32x4 z = {0.f, 0.f, 0.f, 0.f};
    f32x4 acc[2][4];
    #pragma unroll
    for (int i = 0; i < 2; ++i)
        #pragma unroll
        for (int j = 0; j < 4; ++j) acc[i][j] = z;

    for (int k0 = 0; k0 < KCB; k0 += 64) {
        // stage A: read u, scale, write E back (final), f16 to LDS
        {
            size_t off = (size_t)(r0 + arow) * KCB + k0 + akc;
            float4 u0 = *(const float4*)(U + off);
            float4 u1 = *(const float4*)(U + off + 4);
            const float il = invl[arow];
            float e0 = u0.x * il, e1 = u0.y * il, e2 = u0.z * il, e3 = u0.w * il;
            float e4 = u1.x * il, e5 = u1.y * il, e6 = u1.z * il, e7 = u1.w * il;
            *(float4*)(U + off)     = make_float4(e0, e1, e2, e3);
            *(float4*)(U + off + 4) = make_float4(e4, e5, e6, e7);
            f16x8 h;
            h[0] = (f16)e0; h[1] = (f16)e1; h[2] = (f16)e2; h[3] = (f16)e3;
            h[4] = (f16)e4; h[5] = (f16)e5; h[6] = (f16)e6; h[7] = (f16)e7;
            *(f16x8*)(As + arow * 72 + akc) = h;
        }
        // stage B: chT tile [256][64] as two [256][32] halves
        #pragma unroll
        for (int p = 0; p < 8; ++p) {
            int n = p * 256 + tid;       // 16B chunk id
            int hh = n >> 10;            // K-half
            int m = n & 1023;
            int d = m >> 2, c = m & 3;
            lds_async16(chT + (size_t)d * KCB + k0 + hh * 32 + c * 8,
                        (char*)Bs + n * 16);
        }
        __syncthreads();
        #pragma unroll
        for (int ks = 0; ks < 2; ++ks) {
            f16x8 a[2], b[4];
            #pragma unroll
            for (int i = 0; i < 2; ++i)
                a[i] = *(const f16x8*)(As + (i * 16 + fr) * 72 + ks * 32 + fk);
            #pragma unroll
            for (int j = 0; j < 4; ++j)
                b[j] = *(const f16x8*)(Bs + ks * (256 * 32) + (wid * 64 + j * 16 + fr) * 32 + fk);
            #pragma unroll
            for (int i = 0; i < 2; ++i)
                #pragma unroll
                for (int j = 0; j < 4; ++j)
                    acc[i][j] = __builtin_amdgcn_mfma_f32_16x16x32_f16(a[i], b[j], acc[i][j], 0, 0, 0);
        }
        __syncthreads();
    }

    const int rq = (lane >> 4) * 4;
    #pragma unroll
    for (int i = 0; i < 2; ++i)
        #pragma unroll
        for (int j = 0; j < 4; ++j) {
            const int col = wid * 64 + j * 16 + fr;
            #pragma unroll
            for (int r = 0; r < 4; ++r) {
                const int row = r0 + i * 16 + rq + r;
                Q[row * DDIM + col] = acc[i][j][r];
            }
        }
}

extern "C" void kernel_launch(void* const* d_in, const int* in_sizes, int n_in,
                              void* d_out, int out_size, void* d_ws, size_t ws_size,
                              hipStream_t stream) {
    const float* x     = (const float*)d_in[0];
    const float* cb    = (const float*)d_in[1];
    const float* noise = (const float*)d_in[2];

    float* Q   = (float*)d_out;                       // [16384,256]
    float* E   = Q + 4194304;                         // [16384,8192]
    float* IDX = Q + 138412032;                       // [16384]

    char* ws = (char*)d_ws;
    f16* Acat = (f16*)ws;                             // 25,165,824 B
    f16* Bcat = (f16*)(ws + 25165824);                // 12,582,912 B
    f16* chT  = (f16*)(ws + 37748736);                //  4,194,304 B
    float* c2 = (float*)(ws + 41943040);              //     32,768 B
    float* gsum = (float*)(ws + 41975808);            //     65,536 B
    unsigned long long* gmin =
        (unsigned long long*)(ws + 42041344);         //    131,072 B

    init_k<<<64, 256, 0, stream>>>(gsum, gmin);
    prep_x<<<NPIX, 256, 0, stream>>>(x, Acat);
    prep_c<<<KCB, 256, 0, stream>>>(cb, Bcat, c2);
    transpose_c<<<dim3(128, 4), 256, 0, stream>>>(Bcat, chT);
    gemm1<<<dim3(64, 128), 256, 0, stream>>>(Acat, Bcat, c2, noise, E, gsum, gmin);
    gemm2<<<512, 256, 0, stream>>>(E, chT, gsum, gmin, Q, IDX);
}